// Round 1
// baseline (97.705 us; speedup 1.0000x reference)
//
#include <hip/hip_runtime.h>
#include <math.h>

#define NB 8          // NUM_BINS
#define DD 32         // D
constexpr float TB   = 10.0f;   // TAIL_BOUND
constexpr float MBW  = 1e-3f;   // MIN_BIN_WIDTH
constexpr float MBH  = 1e-3f;   // MIN_BIN_HEIGHT
constexpr float MDER = 1e-3f;   // MIN_DERIVATIVE

__device__ __forceinline__ float softplusf(float v) {
    // numerically stable softplus; inputs are ~N(0,1) but guard anyway
    return (v > 20.0f) ? v : log1pf(expf(v));
}

__global__ __launch_bounds__(256) void mfb_kernel(
    const float* __restrict__ x,
    const float* __restrict__ uw,
    const float* __restrict__ uh,
    const float* __restrict__ ud,
    float* __restrict__ out,
    int n4)
{
    __shared__ float s_cumw[DD][NB + 1];
    __shared__ float s_w[DD][NB];
    __shared__ float s_cumh[DD][NB + 1];
    __shared__ float s_h[DD][NB];
    __shared__ float s_d[DD][NB + 1];

    const int t = threadIdx.x;

    if (t < DD) {
        // ---- widths ----
        {
            float u[NB];
            float m = -1e30f;
            #pragma unroll
            for (int k = 0; k < NB; ++k) { u[k] = uw[t * NB + k]; m = fmaxf(m, u[k]); }
            float s = 0.0f;
            #pragma unroll
            for (int k = 0; k < NB; ++k) { u[k] = expf(u[k] - m); s += u[k]; }
            const float inv = 1.0f / s;
            float pos[NB + 1];
            pos[0] = -TB;
            float cum = 0.0f;
            #pragma unroll
            for (int k = 0; k < NB; ++k) {
                float sz = MBW + (1.0f - MBW * (float)NB) * (u[k] * inv);
                cum += sz;
                pos[k + 1] = 2.0f * TB * cum - TB;
            }
            pos[NB] = TB;
            #pragma unroll
            for (int k = 0; k <= NB; ++k) s_cumw[t][k] = pos[k];
            #pragma unroll
            for (int k = 0; k < NB; ++k) s_w[t][k] = pos[k + 1] - pos[k];
        }
        // ---- heights ----
        {
            float u[NB];
            float m = -1e30f;
            #pragma unroll
            for (int k = 0; k < NB; ++k) { u[k] = uh[t * NB + k]; m = fmaxf(m, u[k]); }
            float s = 0.0f;
            #pragma unroll
            for (int k = 0; k < NB; ++k) { u[k] = expf(u[k] - m); s += u[k]; }
            const float inv = 1.0f / s;
            float pos[NB + 1];
            pos[0] = -TB;
            float cum = 0.0f;
            #pragma unroll
            for (int k = 0; k < NB; ++k) {
                float sz = MBH + (1.0f - MBH * (float)NB) * (u[k] * inv);
                cum += sz;
                pos[k + 1] = 2.0f * TB * cum - TB;
            }
            pos[NB] = TB;
            #pragma unroll
            for (int k = 0; k <= NB; ++k) s_cumh[t][k] = pos[k];
            #pragma unroll
            for (int k = 0; k < NB; ++k) s_h[t][k] = pos[k + 1] - pos[k];
        }
        // ---- derivatives ----
        {
            const float c = logf(expm1f(1.0f - MDER));
            const float bnd = MDER + softplusf(c);   // == 1.0 to fp precision
            s_d[t][0]  = bnd;
            s_d[t][NB] = bnd;
            #pragma unroll
            for (int k = 1; k < NB; ++k)
                s_d[t][k] = MDER + softplusf(ud[t * (NB - 1) + (k - 1)]);
        }
    }
    __syncthreads();

    constexpr float HALF_LOG_2PI = 0.91893853320467274178f;

    auto evalone = [&](float xx, int d) -> float {
        const bool inside = (xx >= -TB) && (xx <= TB);
        const float xc = fminf(fmaxf(xx, -TB), TB);
        int idx = 0;
        #pragma unroll
        for (int k = 1; k < NB; ++k) idx += (xc >= s_cumw[d][k]) ? 1 : 0;

        const float cw = s_cumw[d][idx];
        const float w  = s_w[d][idx];
        const float ch = s_cumh[d][idx];
        const float h  = s_h[d][idx];
        const float da = s_d[d][idx];
        const float db = s_d[d][idx + 1];

        const float invw  = 1.0f / w;
        const float delta = h * invw;
        const float theta = (xc - cw) * invw;
        const float omt   = 1.0f - theta;
        const float t1m   = theta * omt;
        const float denom = delta + (da + db - 2.0f * delta) * t1m;
        const float zin   = ch + h * (delta * theta * theta + da * t1m) / denom;
        const float num   = delta * delta *
                            (db * theta * theta + 2.0f * delta * t1m + da * omt * omt);
        const float ld    = __logf(num / (denom * denom));

        const float z = inside ? zin : xx;
        const float l = inside ? ld : 0.0f;
        return -0.5f * z * z - HALF_LOG_2PI + l;
    };

    const float4* __restrict__ x4 = reinterpret_cast<const float4*>(x);
    float4* __restrict__ o4 = reinterpret_cast<float4*>(out);

    const int stride = gridDim.x * blockDim.x;
    for (int i = blockIdx.x * blockDim.x + t; i < n4; i += stride) {
        const float4 xv = x4[i];
        const int d = (i * 4) & (DD - 1);   // 4 consecutive dims, no wrap (D=32)
        float4 r;
        r.x = evalone(xv.x, d + 0);
        r.y = evalone(xv.y, d + 1);
        r.z = evalone(xv.z, d + 2);
        r.w = evalone(xv.w, d + 3);
        o4[i] = r;
    }
}

extern "C" void kernel_launch(void* const* d_in, const int* in_sizes, int n_in,
                              void* d_out, int out_size, void* d_ws, size_t ws_size,
                              hipStream_t stream) {
    const float* x  = (const float*)d_in[0];
    const float* uw = (const float*)d_in[1];
    const float* uh = (const float*)d_in[2];
    const float* ud = (const float*)d_in[3];
    float* out = (float*)d_out;

    const int n4 = in_sizes[0] / 4;                 // N*D/4 float4 elements
    int blocks = (n4 + 255) / 256;
    if (blocks > 2048) blocks = 2048;               // 8 blocks/CU, grid-stride

    mfb_kernel<<<blocks, 256, 0, stream>>>(x, uw, uh, ud, out, n4);
}

// Round 2
// 61.400 us; speedup vs baseline: 1.5913x; 1.5913x over previous
//
#include <hip/hip_runtime.h>
#include <math.h>

#define NB 8          // NUM_BINS
#define DD 32         // D
constexpr float TB   = 10.0f;   // TAIL_BOUND
constexpr float MBW  = 1e-3f;   // MIN_BIN_WIDTH
constexpr float MBH  = 1e-3f;   // MIN_BIN_HEIGHT
constexpr float MDER = 1e-3f;   // MIN_DERIVATIVE

__device__ __forceinline__ float softplusf(float v) {
    return (v > 20.0f) ? v : log1pf(expf(v));
}

__global__ __launch_bounds__(256) void mfb_kernel(
    const float* __restrict__ x,
    const float* __restrict__ uw,
    const float* __restrict__ uh,
    const float* __restrict__ ud,
    float* __restrict__ out,
    int n4)
{
    // knots (cum widths) for the register-resident bin search
    __shared__ float  s_kn[DD][NB + 1];     // 1.1 KB
    // packed per-(dim,bin) tables, XOR-swizzled on bin index by (d>>2)&7
    __shared__ float4 s_A[DD][NB];          // {cw, 1/w, ch, h}      4 KB
    __shared__ float4 s_B[DD][NB];          // {d0, d1, delta, s2}   4 KB

    const int t = threadIdx.x;

    if (t < DD) {
        // ---- widths -> posw ----
        float posw[NB + 1], posh[NB + 1];
        {
            float u[NB];
            float m = -1e30f;
            #pragma unroll
            for (int k = 0; k < NB; ++k) { u[k] = uw[t * NB + k]; m = fmaxf(m, u[k]); }
            float s = 0.0f;
            #pragma unroll
            for (int k = 0; k < NB; ++k) { u[k] = expf(u[k] - m); s += u[k]; }
            const float inv = 1.0f / s;
            posw[0] = -TB;
            float cum = 0.0f;
            #pragma unroll
            for (int k = 0; k < NB; ++k) {
                cum += MBW + (1.0f - MBW * (float)NB) * (u[k] * inv);
                posw[k + 1] = 2.0f * TB * cum - TB;
            }
            posw[NB] = TB;
        }
        // ---- heights -> posh ----
        {
            float u[NB];
            float m = -1e30f;
            #pragma unroll
            for (int k = 0; k < NB; ++k) { u[k] = uh[t * NB + k]; m = fmaxf(m, u[k]); }
            float s = 0.0f;
            #pragma unroll
            for (int k = 0; k < NB; ++k) { u[k] = expf(u[k] - m); s += u[k]; }
            const float inv = 1.0f / s;
            posh[0] = -TB;
            float cum = 0.0f;
            #pragma unroll
            for (int k = 0; k < NB; ++k) {
                cum += MBH + (1.0f - MBH * (float)NB) * (u[k] * inv);
                posh[k + 1] = 2.0f * TB * cum - TB;
            }
            posh[NB] = TB;
        }
        // ---- derivatives ----
        float dv[NB + 1];
        {
            const float c   = logf(expm1f(1.0f - MDER));
            const float bnd = MDER + softplusf(c);   // == 1.0 to fp precision
            dv[0]  = bnd;
            dv[NB] = bnd;
            #pragma unroll
            for (int k = 1; k < NB; ++k)
                dv[k] = MDER + softplusf(ud[t * (NB - 1) + (k - 1)]);
        }
        // ---- publish ----
        #pragma unroll
        for (int k = 0; k <= NB; ++k) s_kn[t][k] = posw[k];
        const int key = (t >> 2) & 7;
        #pragma unroll
        for (int b = 0; b < NB; ++b) {
            const float w     = posw[b + 1] - posw[b];
            const float h     = posh[b + 1] - posh[b];
            const float invw  = 1.0f / w;                    // setup: precise div is fine
            const float delta = h * invw;
            const float s2    = dv[b] + dv[b + 1] - 2.0f * delta;
            s_A[t][b ^ key] = make_float4(posw[b], invw, posh[b], h);
            s_B[t][b ^ key] = make_float4(dv[b], dv[b + 1], delta, s2);
        }
    }
    __syncthreads();

    constexpr float HALF_LOG_2PI = 0.91893853320467274178f;

    const int i0     = blockIdx.x * blockDim.x + t;
    const int stride = gridDim.x * blockDim.x;
    // grid-stride keeps each thread's 4 dims constant (stride*4 % 32 == 0)
    const int dbase  = (i0 * 4) & (DD - 1);
    const int key    = (dbase >> 2) & 7;

    // interior knots in registers: bin search never touches LDS
    float kn[4][7];
    #pragma unroll
    for (int j = 0; j < 4; ++j)
        #pragma unroll
        for (int k = 0; k < 7; ++k)
            kn[j][k] = s_kn[dbase + j][k + 1];

    auto evalone = [&](float xx, int j) -> float {
        const float xc = fminf(fmaxf(xx, -TB), TB);
        int idx = 0;
        #pragma unroll
        for (int k = 0; k < 7; ++k) idx += (xc >= kn[j][k]) ? 1 : 0;

        const int bb = idx ^ key;
        const float4 A = s_A[dbase + j][bb];   // {cw, invw, ch, h}
        const float4 B = s_B[dbase + j][bb];   // {d0, d1, delta, s2}

        const float theta = (xc - A.x) * A.y;
        const float tt    = theta * theta;
        const float omt   = 1.0f - theta;
        const float t1m   = theta * omt;
        const float denom = fmaf(B.w, t1m, B.z);
        const float rden  = __builtin_amdgcn_rcpf(denom);
        const float zin   = fmaf(A.w * fmaf(B.z, tt, B.x * t1m), rden, A.z);
        const float twod  = B.z + B.z;
        const float p     = fmaf(B.y, tt, fmaf(twod, t1m, B.x * (omt * omt)));
        const float num   = (B.z * B.z) * p;
        const float ld    = __logf(num * rden * rden);

        const bool inside = fabsf(xx) <= TB;
        const float z   = inside ? zin : xx;
        const float acc = inside ? ld : 0.0f;
        return fmaf(z * z, -0.5f, acc) - HALF_LOG_2PI;
    };

    const float4* __restrict__ x4 = reinterpret_cast<const float4*>(x);
    float4* __restrict__ o4 = reinterpret_cast<float4*>(out);

    for (int i = i0; i < n4; i += stride) {
        const float4 xv = x4[i];
        float4 r;
        r.x = evalone(xv.x, 0);
        r.y = evalone(xv.y, 1);
        r.z = evalone(xv.z, 2);
        r.w = evalone(xv.w, 3);
        o4[i] = r;
    }
}

extern "C" void kernel_launch(void* const* d_in, const int* in_sizes, int n_in,
                              void* d_out, int out_size, void* d_ws, size_t ws_size,
                              hipStream_t stream) {
    const float* x  = (const float*)d_in[0];
    const float* uw = (const float*)d_in[1];
    const float* uh = (const float*)d_in[2];
    const float* ud = (const float*)d_in[3];
    float* out = (float*)d_out;

    const int n4 = in_sizes[0] / 4;                 // N*D/4 float4 elements
    int blocks = (n4 + 255) / 256;
    if (blocks > 2048) blocks = 2048;               // grid-stride, dims stay fixed per thread

    mfb_kernel<<<blocks, 256, 0, stream>>>(x, uw, uh, ud, out, n4);
}